// Round 1
// baseline (319.301 us; speedup 1.0000x reference)
//
#include <hip/hip_runtime.h>

#define D 256
#define BATCH 512
#define NTOK 8
#define QT 32
#define PPW 8   // p values per workgroup

using f32x4  = __attribute__((ext_vector_type(4))) float;
using bf16x8 = __attribute__((ext_vector_type(8))) short;

__device__ __forceinline__ unsigned short f2bf(float x) {
    unsigned int u = __float_as_uint(x);
    unsigned int r = (u + 0x7fffu + ((u >> 16) & 1u)) >> 16;  // RNE
    return (unsigned short)r;
}

// ---------------------------------------------------------------------------
// Prep: weighted embedding aggregation -> bf16 pre-swizzled A-fragment layout
// verb_pre/subj_pre layout: [mtg=c/16][ks=d/32][lane][8]
//   A-frag (16x16x32): lane l holds A[m=l&15][k=8*(l>>4)+j]
// objswz layout: [mtg][p=d][16 rows] matching C/D row = 4*(lane>>4)+reg
// ---------------------------------------------------------------------------
__global__ __launch_bounds__(256) void prep_kernel(
    const int* __restrict__ subj_id, const float* __restrict__ subj_w,
    const int* __restrict__ verb_id, const float* __restrict__ verb_w,
    const int* __restrict__ obj_id,  const float* __restrict__ obj_w,
    const float* __restrict__ emb,
    unsigned short* __restrict__ verb_pre,
    unsigned short* __restrict__ subj_pre,
    float* __restrict__ objswz)
{
    int c = blockIdx.x;
    int d = threadIdx.x;
    float sv = 0.f, vv = 0.f, ov = 0.f;
#pragma unroll
    for (int n = 0; n < NTOK; ++n) {
        sv += subj_w[c*NTOK+n] * emb[(size_t)subj_id[c*NTOK+n]*D + d];
        vv += verb_w[c*NTOK+n] * emb[(size_t)verb_id[c*NTOK+n]*D + d];
        ov += obj_w [c*NTOK+n] * emb[(size_t)obj_id [c*NTOK+n]*D + d];
    }
    int mtg = c >> 4, r = c & 15;
    int ks = d >> 5, kk = d & 31;
    int lane = ((kk >> 3) << 4) | r;
    int j = kk & 7;
    int idx = ((mtg*8 + ks)*64 + lane)*8 + j;
    verb_pre[idx] = f2bf(vv);
    subj_pre[idx] = f2bf(sv);
    objswz[(size_t)(mtg*D + d)*16 + r] = ov;
}

// ---------------------------------------------------------------------------
// Main fused kernel.
// grid 256 = 8 q-tiles x 32 p-chunks ; bid = qt*32+pc so same-pc WGs share XCD
// block 512 = 8 waves ; wave wv owns c-rows [wv*64, wv*64+64), all 32 q
// Per p: stage w/u slices (fp32->bf16) to LDS transposed [q][i] (+8 pad),
//        A-gemm (verb x w) and US-gemm (subj x u) via 16x16x32 bf16 MFMA,
//        accF += obj[c,p] * A * US. Final: atomicAdd into out.
// ---------------------------------------------------------------------------
__global__ __launch_bounds__(512, 2) void main_kernel(
    const float* __restrict__ wmat, const float* __restrict__ umat,
    const unsigned short* __restrict__ verb_pre,
    const unsigned short* __restrict__ subj_pre,
    const float* __restrict__ objswz,
    float* __restrict__ out)
{
    __shared__ unsigned short wT[QT][D + 8];
    __shared__ unsigned short uT[QT][D + 8];

    int bid = blockIdx.x;
    int qt = bid >> 5;       // 0..7
    int pc = bid & 31;       // 0..31
    int q0 = qt * QT;
    int p0 = pc * PPW;

    int tid  = threadIdx.x;
    int wv   = tid >> 6;     // 0..7
    int lane = tid & 63;
    int g    = lane >> 4;    // 0..3
    int r16  = lane & 15;

    // staging role: threads 0..255 stage w, 256..511 stage u
    int st = tid & 255;
    const float* smat = (tid < 256) ? wmat : umat;
    unsigned short (*sT)[D + 8] = (tid < 256) ? wT : uT;
    int sa = st >> 3;        // 0..31 -> i-row pair
    int qc = (st & 7) * 4;   // q offset within tile

    f32x4 accF[4][2];
#pragma unroll
    for (int mt = 0; mt < 4; ++mt)
#pragma unroll
        for (int nt = 0; nt < 2; ++nt)
            accF[mt][nt] = (f32x4){0.f, 0.f, 0.f, 0.f};

    for (int pi = 0; pi < PPW; ++pi) {
        int p = p0 + pi;
        __syncthreads();   // previous iter's LDS reads done
        // ---- stage slice [256 i][32 q] fp32 -> bf16 transposed [q][i] ----
#pragma unroll
        for (int m = 0; m < 4; ++m) {
            int i0 = m*64 + sa*2;
            const float* base = smat + (size_t)i0*(D*D) + (size_t)p*D + q0 + qc;
            float4 f0 = *(const float4*)base;
            float4 f1 = *(const float4*)(base + D*D);
            unsigned int v0 = (unsigned int)f2bf(f0.x) | ((unsigned int)f2bf(f1.x) << 16);
            unsigned int v1 = (unsigned int)f2bf(f0.y) | ((unsigned int)f2bf(f1.y) << 16);
            unsigned int v2 = (unsigned int)f2bf(f0.z) | ((unsigned int)f2bf(f1.z) << 16);
            unsigned int v3 = (unsigned int)f2bf(f0.w) | ((unsigned int)f2bf(f1.w) << 16);
            *(unsigned int*)&sT[qc+0][i0] = v0;
            *(unsigned int*)&sT[qc+1][i0] = v1;
            *(unsigned int*)&sT[qc+2][i0] = v2;
            *(unsigned int*)&sT[qc+3][i0] = v3;
        }
        __syncthreads();

        // ---- two GEMMs over k = 256 ----
        f32x4 accA[4][2], accU[4][2];
#pragma unroll
        for (int mt = 0; mt < 4; ++mt)
#pragma unroll
            for (int nt = 0; nt < 2; ++nt) {
                accA[mt][nt] = (f32x4){0.f, 0.f, 0.f, 0.f};
                accU[mt][nt] = (f32x4){0.f, 0.f, 0.f, 0.f};
            }

#pragma unroll
        for (int ks = 0; ks < 8; ++ks) {
            bf16x8 av[4], au[4];
#pragma unroll
            for (int mt = 0; mt < 4; ++mt) {
                int mtg = wv*4 + mt;
                size_t off = (size_t)(((mtg*8 + ks)*64) + lane) * 8;
                av[mt] = *(const bf16x8*)(verb_pre + off);
                au[mt] = *(const bf16x8*)(subj_pre + off);
            }
            bf16x8 bw[2], bu[2];
#pragma unroll
            for (int nt = 0; nt < 2; ++nt) {
                int n = nt*16 + r16;
                bw[nt] = *(const bf16x8*)&wT[n][ks*32 + g*8];
                bu[nt] = *(const bf16x8*)&uT[n][ks*32 + g*8];
            }
#pragma unroll
            for (int mt = 0; mt < 4; ++mt)
#pragma unroll
                for (int nt = 0; nt < 2; ++nt) {
                    accA[mt][nt] = __builtin_amdgcn_mfma_f32_16x16x32_bf16(
                        av[mt], bw[nt], accA[mt][nt], 0, 0, 0);
                    accU[mt][nt] = __builtin_amdgcn_mfma_f32_16x16x32_bf16(
                        au[mt], bu[nt], accU[mt][nt], 0, 0, 0);
                }
        }

        // ---- fuse: accF += obj[c,p] * A * US ----
#pragma unroll
        for (int mt = 0; mt < 4; ++mt) {
            int mtg = wv*4 + mt;
            f32x4 ob = *(const f32x4*)(objswz + (size_t)(mtg*D + p)*16 + g*4);
#pragma unroll
            for (int nt = 0; nt < 2; ++nt)
#pragma unroll
                for (int rr = 0; rr < 4; ++rr)
                    accF[mt][nt][rr] += ob[rr] * accA[mt][nt][rr] * accU[mt][nt][rr];
        }
    }

    // ---- accumulate partials over p-chunks ----
#pragma unroll
    for (int mt = 0; mt < 4; ++mt)
#pragma unroll
        for (int nt = 0; nt < 2; ++nt)
#pragma unroll
            for (int rr = 0; rr < 4; ++rr) {
                int c = wv*64 + mt*16 + g*4 + rr;
                int q = q0 + nt*16 + r16;
                atomicAdd(&out[(size_t)c*D + q], accF[mt][nt][rr]);
            }
}

extern "C" void kernel_launch(void* const* d_in, const int* in_sizes, int n_in,
                              void* d_out, int out_size, void* d_ws, size_t ws_size,
                              hipStream_t stream) {
    const int*   subj_id = (const int*)  d_in[0];
    const float* subj_w  = (const float*)d_in[1];
    const int*   verb_id = (const int*)  d_in[2];
    const float* verb_w  = (const float*)d_in[3];
    const int*   obj_id  = (const int*)  d_in[4];
    const float* obj_w   = (const float*)d_in[5];
    const float* emb     = (const float*)d_in[6];
    const float* wmat    = (const float*)d_in[7];
    const float* umat    = (const float*)d_in[8];
    float* out = (float*)d_out;

    unsigned short* verb_pre = (unsigned short*)d_ws;                  // 256 KB
    unsigned short* subj_pre = verb_pre + BATCH*D;                     // 256 KB
    float* objswz = (float*)((char*)d_ws + 2*BATCH*D*sizeof(unsigned short)); // 512 KB

    hipMemsetAsync(out, 0, (size_t)out_size * sizeof(float), stream);
    prep_kernel<<<BATCH, D, 0, stream>>>(subj_id, subj_w, verb_id, verb_w,
                                         obj_id, obj_w, emb,
                                         verb_pre, subj_pre, objswz);
    main_kernel<<<256, 512, 0, stream>>>(wmat, umat, verb_pre, subj_pre, objswz, out);
}

// Round 2
// 313.435 us; speedup vs baseline: 1.0187x; 1.0187x over previous
//
#include <hip/hip_runtime.h>

#define D 256
#define BATCH 512
#define NTOK 8
#define QT 32
#define PPW 8
#define PAD 10  // row stride = 266 shorts = 133 dwords (odd) -> conflict-free transposed writes

using f32x4  = __attribute__((ext_vector_type(4))) float;
using bf16x8 = __attribute__((ext_vector_type(8))) short;

__device__ __forceinline__ unsigned short f2bf(float x) {
    unsigned int u = __float_as_uint(x);
    unsigned int r = (u + 0x7fffu + ((u >> 16) & 1u)) >> 16;  // RNE
    return (unsigned short)r;
}

// ---------------------------------------------------------------------------
// Prep: weighted embedding aggregation -> bf16 pre-swizzled A-fragment layout,
// obj in C/D-row-swizzled layout, and zero-init of out (replaces memset).
// verb_pre/subj_pre: [mtg=c/16][ks=d/32][lane][8]  (A-frag for 16x16x32)
// objswz: [mtg][p=d][16 rows], row matches C/D row = 4*(lane>>4)+reg
// ---------------------------------------------------------------------------
__global__ __launch_bounds__(256) void prep_kernel(
    const int* __restrict__ subj_id, const float* __restrict__ subj_w,
    const int* __restrict__ verb_id, const float* __restrict__ verb_w,
    const int* __restrict__ obj_id,  const float* __restrict__ obj_w,
    const float* __restrict__ emb,
    unsigned short* __restrict__ verb_pre,
    unsigned short* __restrict__ subj_pre,
    float* __restrict__ objswz,
    float* __restrict__ out)
{
    int c = blockIdx.x;
    int d = threadIdx.x;
    float sv = 0.f, vv = 0.f, ov = 0.f;
#pragma unroll
    for (int n = 0; n < NTOK; ++n) {
        sv += subj_w[c*NTOK+n] * emb[(size_t)subj_id[c*NTOK+n]*D + d];
        vv += verb_w[c*NTOK+n] * emb[(size_t)verb_id[c*NTOK+n]*D + d];
        ov += obj_w [c*NTOK+n] * emb[(size_t)obj_id [c*NTOK+n]*D + d];
    }
    int mtg = c >> 4, r = c & 15;
    int ks = d >> 5, kk = d & 31;
    int lane = ((kk >> 3) << 4) | r;
    int j = kk & 7;
    int idx = ((mtg*8 + ks)*64 + lane)*8 + j;
    verb_pre[idx] = f2bf(vv);
    subj_pre[idx] = f2bf(sv);
    objswz[(size_t)(mtg*D + d)*16 + r] = ov;
    out[(size_t)c*D + d] = 0.f;   // harness poisons d_out before every launch
}

// ---------------------------------------------------------------------------
// Main fused kernel. grid 256 = 8 qt x 32 pc ; block 512 = 8 waves.
// Per p: stage w/u [256 i][32 q] fp32->bf16 transposed into LDS (nontemporal
// loads, reg-prefetched one p ahead), two bf16 MFMA GEMMs over k=256,
// accF += obj[c,p]*A*US. Epilogue: atomicAdd into out.
// ---------------------------------------------------------------------------
__global__ __launch_bounds__(512, 1) void main_kernel(
    const float* __restrict__ wmat, const float* __restrict__ umat,
    const unsigned short* __restrict__ verb_pre,
    const unsigned short* __restrict__ subj_pre,
    const float* __restrict__ objswz,
    float* __restrict__ out)
{
    __shared__ unsigned short wT[QT][D + PAD];
    __shared__ unsigned short uT[QT][D + PAD];

    int bid = blockIdx.x;
    int qt = bid >> 5;       // 0..7
    int pc = bid & 31;       // 0..31  (all 8 qt of one pc land on one XCD)
    int q0 = qt * QT;
    int p0 = pc * PPW;

    int tid  = threadIdx.x;
    int wv   = tid >> 6;     // 0..7
    int lane = tid & 63;
    int g    = lane >> 4;    // 0..3
    int r16  = lane & 15;

    // staging role: threads 0..255 stage w, 256..511 stage u
    int st = tid & 255;
    const float* smat = (tid < 256) ? wmat : umat;
    unsigned short (*sT)[D + PAD] = (tid < 256) ? wT : uT;
    int sa = st >> 3;        // 0..31 -> i-row pair base
    int qc = (st & 7) * 4;   // q offset within tile

    f32x4 accF[4][2];
#pragma unroll
    for (int mt = 0; mt < 4; ++mt)
#pragma unroll
        for (int nt = 0; nt < 2; ++nt)
            accF[mt][nt] = (f32x4){0.f, 0.f, 0.f, 0.f};

    // prefetch buffer: [m][row-pair]
    f32x4 pf[4][2];

    // prologue: issue loads for pi = 0
#pragma unroll
    for (int m = 0; m < 4; ++m) {
        const f32x4* base = (const f32x4*)(smat + (size_t)(m*64 + sa*2)*(D*D)
                                               + (size_t)p0*D + q0 + qc);
        pf[m][0] = __builtin_nontemporal_load(base);
        pf[m][1] = __builtin_nontemporal_load(base + (D*D)/4);
    }

    for (int pi = 0; pi < PPW; ++pi) {
        __syncthreads();   // previous iter's LDS reads done

        // ---- convert + transposed LDS write (waits on pf's vmcnt) ----
#pragma unroll
        for (int m = 0; m < 4; ++m) {
            int i0 = m*64 + sa*2;
            f32x4 f0 = pf[m][0];
            f32x4 f1 = pf[m][1];
            unsigned int v0 = (unsigned int)f2bf(f0[0]) | ((unsigned int)f2bf(f1[0]) << 16);
            unsigned int v1 = (unsigned int)f2bf(f0[1]) | ((unsigned int)f2bf(f1[1]) << 16);
            unsigned int v2 = (unsigned int)f2bf(f0[2]) | ((unsigned int)f2bf(f1[2]) << 16);
            unsigned int v3 = (unsigned int)f2bf(f0[3]) | ((unsigned int)f2bf(f1[3]) << 16);
            *(unsigned int*)&sT[qc+0][i0] = v0;
            *(unsigned int*)&sT[qc+1][i0] = v1;
            *(unsigned int*)&sT[qc+2][i0] = v2;
            *(unsigned int*)&sT[qc+3][i0] = v3;
        }

        // ---- issue next-p loads into the (now consumed) buffer ----
        if (pi + 1 < PPW) {
            int pn = p0 + pi + 1;
#pragma unroll
            for (int m = 0; m < 4; ++m) {
                const f32x4* base = (const f32x4*)(smat + (size_t)(m*64 + sa*2)*(D*D)
                                                       + (size_t)pn*D + q0 + qc);
                pf[m][0] = __builtin_nontemporal_load(base);
                pf[m][1] = __builtin_nontemporal_load(base + (D*D)/4);
            }
        }
        __syncthreads();

        // ---- two GEMMs over k = 256 ----
        int p = p0 + pi;
        f32x4 accA[4][2], accU[4][2];
#pragma unroll
        for (int mt = 0; mt < 4; ++mt)
#pragma unroll
            for (int nt = 0; nt < 2; ++nt) {
                accA[mt][nt] = (f32x4){0.f, 0.f, 0.f, 0.f};
                accU[mt][nt] = (f32x4){0.f, 0.f, 0.f, 0.f};
            }

#pragma unroll
        for (int ks = 0; ks < 8; ++ks) {
            bf16x8 av[4], au[4];
#pragma unroll
            for (int mt = 0; mt < 4; ++mt) {
                int mtg = wv*4 + mt;
                size_t off = (size_t)(((mtg*8 + ks)*64) + lane) * 8;
                av[mt] = *(const bf16x8*)(verb_pre + off);
                au[mt] = *(const bf16x8*)(subj_pre + off);
            }
            bf16x8 bw[2], bu[2];
#pragma unroll
            for (int nt = 0; nt < 2; ++nt) {
                int n = nt*16 + r16;
                bw[nt] = *(const bf16x8*)&wT[n][ks*32 + g*8];
                bu[nt] = *(const bf16x8*)&uT[n][ks*32 + g*8];
            }
#pragma unroll
            for (int mt = 0; mt < 4; ++mt)
#pragma unroll
                for (int nt = 0; nt < 2; ++nt) {
                    accA[mt][nt] = __builtin_amdgcn_mfma_f32_16x16x32_bf16(
                        av[mt], bw[nt], accA[mt][nt], 0, 0, 0);
                    accU[mt][nt] = __builtin_amdgcn_mfma_f32_16x16x32_bf16(
                        au[mt], bu[nt], accU[mt][nt], 0, 0, 0);
                }
        }

        // ---- fuse: accF += obj[c,p] * A * US ----
#pragma unroll
        for (int mt = 0; mt < 4; ++mt) {
            int mtg = wv*4 + mt;
            f32x4 ob = *(const f32x4*)(objswz + (size_t)(mtg*D + p)*16 + g*4);
#pragma unroll
            for (int nt = 0; nt < 2; ++nt)
#pragma unroll
                for (int rr = 0; rr < 4; ++rr)
                    accF[mt][nt][rr] += ob[rr] * accA[mt][nt][rr] * accU[mt][nt][rr];
        }
    }

    // ---- accumulate partials over p-chunks ----
#pragma unroll
    for (int mt = 0; mt < 4; ++mt)
#pragma unroll
        for (int nt = 0; nt < 2; ++nt)
#pragma unroll
            for (int rr = 0; rr < 4; ++rr) {
                int c = wv*64 + mt*16 + g*4 + rr;
                int q = q0 + nt*16 + r16;
                atomicAdd(&out[(size_t)c*D + q], accF[mt][nt][rr]);
            }
}

extern "C" void kernel_launch(void* const* d_in, const int* in_sizes, int n_in,
                              void* d_out, int out_size, void* d_ws, size_t ws_size,
                              hipStream_t stream) {
    const int*   subj_id = (const int*)  d_in[0];
    const float* subj_w  = (const float*)d_in[1];
    const int*   verb_id = (const int*)  d_in[2];
    const float* verb_w  = (const float*)d_in[3];
    const int*   obj_id  = (const int*)  d_in[4];
    const float* obj_w   = (const float*)d_in[5];
    const float* emb     = (const float*)d_in[6];
    const float* wmat    = (const float*)d_in[7];
    const float* umat    = (const float*)d_in[8];
    float* out = (float*)d_out;

    unsigned short* verb_pre = (unsigned short*)d_ws;                  // 256 KB
    unsigned short* subj_pre = verb_pre + BATCH*D;                     // 256 KB
    float* objswz = (float*)((char*)d_ws + 2*BATCH*D*sizeof(unsigned short)); // 512 KB

    prep_kernel<<<BATCH, D, 0, stream>>>(subj_id, subj_w, verb_id, verb_w,
                                         obj_id, obj_w, emb,
                                         verb_pre, subj_pre, objswz, out);
    main_kernel<<<256, 512, 0, stream>>>(wmat, umat, verb_pre, subj_pre, objswz, out);
}

// Round 3
// 221.475 us; speedup vs baseline: 1.4417x; 1.4152x over previous
//
#include <hip/hip_runtime.h>

#define D 256
#define BATCH 512
#define NTOK 8
#define QT 32
#define PPW 16
#define PAD 10  // row stride = 266 shorts = 133 dwords (odd)

using f32x4  = __attribute__((ext_vector_type(4))) float;
using bf16x8 = __attribute__((ext_vector_type(8))) short;

__device__ __forceinline__ unsigned short f2bf(float x) {
    unsigned int u = __float_as_uint(x);
    unsigned int r = (u + 0x7fffu + ((u >> 16) & 1u)) >> 16;  // RNE
    return (unsigned short)r;
}

// ---------------------------------------------------------------------------
// Prep: weighted embedding aggregation -> bf16 A-fragment layout + swizzled
// obj + zero-init of out.
// verb_pre/subj_pre: [mtg=c/16][ks=d/32][lane][8]  (A-frag for 16x16x32)
// objswz: [mtg][p=d][16 rows], row matches C/D row = 4*(lane>>4)+reg
// ---------------------------------------------------------------------------
__global__ __launch_bounds__(256) void prep_kernel(
    const int* __restrict__ subj_id, const float* __restrict__ subj_w,
    const int* __restrict__ verb_id, const float* __restrict__ verb_w,
    const int* __restrict__ obj_id,  const float* __restrict__ obj_w,
    const float* __restrict__ emb,
    unsigned short* __restrict__ verb_pre,
    unsigned short* __restrict__ subj_pre,
    float* __restrict__ objswz,
    float* __restrict__ out)
{
    int c = blockIdx.x;
    int d = threadIdx.x;
    float sv = 0.f, vv = 0.f, ov = 0.f;
#pragma unroll
    for (int n = 0; n < NTOK; ++n) {
        sv += subj_w[c*NTOK+n] * emb[(size_t)subj_id[c*NTOK+n]*D + d];
        vv += verb_w[c*NTOK+n] * emb[(size_t)verb_id[c*NTOK+n]*D + d];
        ov += obj_w [c*NTOK+n] * emb[(size_t)obj_id [c*NTOK+n]*D + d];
    }
    int mtg = c >> 4, r = c & 15;
    int ks = d >> 5, kk = d & 31;
    int lane = ((kk >> 3) << 4) | r;
    int j = kk & 7;
    int idx = ((mtg*8 + ks)*64 + lane)*8 + j;
    verb_pre[idx] = f2bf(vv);
    subj_pre[idx] = f2bf(sv);
    objswz[(size_t)(mtg*D + d)*16 + r] = ov;
    out[(size_t)c*D + d] = 0.f;
}

// ---------------------------------------------------------------------------
// Main fused kernel — A-fragments register-resident.
// grid 256 = 2 ct x 8 qt x 16 pc ; bid = ct*128 + qt*16 + pc so the two
// ct-partners sharing each w/u slice sit on the same XCD (bid%8 equal).
// block 512 = 8 waves ; wave wv owns c-rows [ct*256 + wv*32, +32), 32 q.
// Prologue: load A-frags (verb/subj, 128 VGPR) once.
// Per p: stage w/u [256 i][32 q] fp32->bf16 transposed into LDS (prefetched
// one p ahead in regs), 8 k-steps x 8 MFMA from registers, obj-fused
// accumulate. Epilogue: atomicAdd into out.
// ---------------------------------------------------------------------------
__global__ __launch_bounds__(512, 2) void main_kernel(
    const float* __restrict__ wmat, const float* __restrict__ umat,
    const unsigned short* __restrict__ verb_pre,
    const unsigned short* __restrict__ subj_pre,
    const float* __restrict__ objswz,
    float* __restrict__ out)
{
    __shared__ unsigned short wT[QT][D + PAD];
    __shared__ unsigned short uT[QT][D + PAD];

    int bid = blockIdx.x;
    int ct  = bid >> 7;        // 0..1
    int grp = bid & 127;
    int qt  = grp >> 4;        // 0..7
    int pc  = grp & 15;        // 0..15
    int q0 = qt * QT;
    int p0 = pc * PPW;

    int tid  = threadIdx.x;
    int wv   = tid >> 6;       // 0..7
    int lane = tid & 63;
    int g    = lane >> 4;      // 0..3
    int r16  = lane & 15;

    // staging role: threads 0..255 stage w, 256..511 stage u
    int st = tid & 255;
    const float* smat = (tid < 256) ? wmat : umat;
    unsigned short (*sT)[D + PAD] = (tid < 256) ? wT : uT;
    int sa = st >> 3;          // 0..31 -> i-row-pair base
    int qc = (st & 7) * 4;     // q offset within tile

    // ---- prologue: stage loads for pi=0, then A-frag loads ----
    f32x4 pf[4][2];
#pragma unroll
    for (int m = 0; m < 4; ++m) {
        const f32x4* base = (const f32x4*)(smat + (size_t)(m*64 + sa*2)*(D*D)
                                               + (size_t)p0*D + q0 + qc);
        pf[m][0] = *base;
        pf[m][1] = *(base + (D*D)/4);
    }

    bf16x8 av[2][8], au[2][8];   // A-frags: 32 c-rows x K=256, both matrices
#pragma unroll
    for (int mt = 0; mt < 2; ++mt) {
        int mtg = ct*16 + wv*2 + mt;
#pragma unroll
        for (int ks = 0; ks < 8; ++ks) {
            size_t off = (size_t)(((mtg*8 + ks)*64) + lane) * 8;
            av[mt][ks] = *(const bf16x8*)(verb_pre + off);
            au[mt][ks] = *(const bf16x8*)(subj_pre + off);
        }
    }

    f32x4 accF[2][2];
#pragma unroll
    for (int mt = 0; mt < 2; ++mt)
#pragma unroll
        for (int nt = 0; nt < 2; ++nt)
            accF[mt][nt] = (f32x4){0.f, 0.f, 0.f, 0.f};

#pragma unroll 1
    for (int pi = 0; pi < PPW; ++pi) {
        __syncthreads();   // previous iter's LDS reads done

        // ---- convert + transposed LDS write ----
#pragma unroll
        for (int m = 0; m < 4; ++m) {
            int i0 = m*64 + sa*2;
            f32x4 f0 = pf[m][0];
            f32x4 f1 = pf[m][1];
#pragma unroll
            for (int j = 0; j < 4; ++j) {
                unsigned int v = (unsigned int)f2bf(f0[j])
                               | ((unsigned int)f2bf(f1[j]) << 16);
                *(unsigned int*)&sT[qc+j][i0] = v;
            }
        }

        // ---- issue next-p stage loads into the consumed pf regs ----
        if (pi + 1 < PPW) {
            int pn = p0 + pi + 1;
#pragma unroll
            for (int m = 0; m < 4; ++m) {
                const f32x4* base = (const f32x4*)(smat + (size_t)(m*64 + sa*2)*(D*D)
                                                       + (size_t)pn*D + q0 + qc);
                pf[m][0] = *base;
                pf[m][1] = *(base + (D*D)/4);
            }
        }
        __syncthreads();

        int p = p0 + pi;
        // obj scales for this p (per mt, rows g*4..g*4+3)
        f32x4 ob[2];
#pragma unroll
        for (int mt = 0; mt < 2; ++mt) {
            int mtg = ct*16 + wv*2 + mt;
            ob[mt] = *(const f32x4*)(objswz + ((size_t)mtg*D + p)*16 + g*4);
        }

#pragma unroll
        for (int nt = 0; nt < 2; ++nt) {
            f32x4 aA[2], aU[2];
#pragma unroll
            for (int mt = 0; mt < 2; ++mt) {
                aA[mt] = (f32x4){0.f, 0.f, 0.f, 0.f};
                aU[mt] = (f32x4){0.f, 0.f, 0.f, 0.f};
            }
#pragma unroll
            for (int ks = 0; ks < 8; ++ks) {
                bf16x8 bw = *(const bf16x8*)&wT[nt*16 + r16][ks*32 + g*8];
                bf16x8 bu = *(const bf16x8*)&uT[nt*16 + r16][ks*32 + g*8];
#pragma unroll
                for (int mt = 0; mt < 2; ++mt) {
                    aA[mt] = __builtin_amdgcn_mfma_f32_16x16x32_bf16(
                        av[mt][ks], bw, aA[mt], 0, 0, 0);
                    aU[mt] = __builtin_amdgcn_mfma_f32_16x16x32_bf16(
                        au[mt][ks], bu, aU[mt], 0, 0, 0);
                }
            }
#pragma unroll
            for (int mt = 0; mt < 2; ++mt)
#pragma unroll
                for (int rr = 0; rr < 4; ++rr)
                    accF[mt][nt][rr] += ob[mt][rr] * aA[mt][rr] * aU[mt][rr];
        }
    }

    // ---- accumulate partials over p-chunks ----
#pragma unroll
    for (int mt = 0; mt < 2; ++mt)
#pragma unroll
        for (int nt = 0; nt < 2; ++nt)
#pragma unroll
            for (int rr = 0; rr < 4; ++rr) {
                int c = ct*256 + wv*32 + mt*16 + g*4 + rr;
                int q = q0 + nt*16 + r16;
                atomicAdd(&out[(size_t)c*D + q], accF[mt][nt][rr]);
            }
}

extern "C" void kernel_launch(void* const* d_in, const int* in_sizes, int n_in,
                              void* d_out, int out_size, void* d_ws, size_t ws_size,
                              hipStream_t stream) {
    const int*   subj_id = (const int*)  d_in[0];
    const float* subj_w  = (const float*)d_in[1];
    const int*   verb_id = (const int*)  d_in[2];
    const float* verb_w  = (const float*)d_in[3];
    const int*   obj_id  = (const int*)  d_in[4];
    const float* obj_w   = (const float*)d_in[5];
    const float* emb     = (const float*)d_in[6];
    const float* wmat    = (const float*)d_in[7];
    const float* umat    = (const float*)d_in[8];
    float* out = (float*)d_out;

    unsigned short* verb_pre = (unsigned short*)d_ws;                  // 256 KB
    unsigned short* subj_pre = verb_pre + BATCH*D;                     // 256 KB
    float* objswz = (float*)((char*)d_ws + 2*BATCH*D*sizeof(unsigned short)); // 512 KB

    prep_kernel<<<BATCH, D, 0, stream>>>(subj_id, subj_w, verb_id, verb_w,
                                         obj_id, obj_w, emb,
                                         verb_pre, subj_pre, objswz, out);
    main_kernel<<<256, 512, 0, stream>>>(wmat, umat, verb_pre, subj_pre, objswz, out);
}

// Round 4
// 219.416 us; speedup vs baseline: 1.4552x; 1.0094x over previous
//
#include <hip/hip_runtime.h>

#define D 256
#define BATCH 512
#define NTOK 8
#define QT 32
#define PPW 16

using f32x4  = __attribute__((ext_vector_type(4))) float;
using bf16x8 = __attribute__((ext_vector_type(8))) short;

__device__ __forceinline__ unsigned short f2bf(float x) {
    unsigned int u = __float_as_uint(x);
    unsigned int r = (u + 0x7fffu + ((u >> 16) & 1u)) >> 16;  // RNE
    return (unsigned short)r;
}

// ---------------------------------------------------------------------------
// Prep: weighted embedding aggregation -> bf16 A-fragment layout + swizzled
// obj + zero-init of out.
// verb_pre/subj_pre: [mtg=c/16][ks=d/32][lane][8]  (A-frag for 16x16x32)
// objswz: [mtg][p=d][16 rows], row matches C/D row = 4*(lane>>4)+reg
// ---------------------------------------------------------------------------
__global__ __launch_bounds__(256) void prep_kernel(
    const int* __restrict__ subj_id, const float* __restrict__ subj_w,
    const int* __restrict__ verb_id, const float* __restrict__ verb_w,
    const int* __restrict__ obj_id,  const float* __restrict__ obj_w,
    const float* __restrict__ emb,
    unsigned short* __restrict__ verb_pre,
    unsigned short* __restrict__ subj_pre,
    float* __restrict__ objswz,
    float* __restrict__ out)
{
    int c = blockIdx.x;
    int d = threadIdx.x;
    float sv = 0.f, vv = 0.f, ov = 0.f;
#pragma unroll
    for (int n = 0; n < NTOK; ++n) {
        sv += subj_w[c*NTOK+n] * emb[(size_t)subj_id[c*NTOK+n]*D + d];
        vv += verb_w[c*NTOK+n] * emb[(size_t)verb_id[c*NTOK+n]*D + d];
        ov += obj_w [c*NTOK+n] * emb[(size_t)obj_id [c*NTOK+n]*D + d];
    }
    int mtg = c >> 4, r = c & 15;
    int ks = d >> 5, kk = d & 31;
    int lane = ((kk >> 3) << 4) | r;
    int j = kk & 7;
    int idx = ((mtg*8 + ks)*64 + lane)*8 + j;
    verb_pre[idx] = f2bf(vv);
    subj_pre[idx] = f2bf(sv);
    objswz[(size_t)(mtg*D + d)*16 + r] = ov;
    out[(size_t)c*D + d] = 0.f;
}

// ---------------------------------------------------------------------------
// Main fused kernel — A register-resident, fragment-linear LDS, double-buffer.
// grid 256 = 2 ct x 8 qt x 16 pc ; block 512 = 8 waves; wave owns 32c x 32q.
// LDS Bl[buf][ks][mat][nt][lane][8]: each B-fragment is a contiguous 1KB block
// read at base+lane*16 (conflict-free); staging writes are lane-linear 512B
// runs (conflict-free). One barrier per pi; convert+write overlap MFMA.
// ---------------------------------------------------------------------------
__global__ __launch_bounds__(512, 1) void main_kernel(
    const float* __restrict__ wmat, const float* __restrict__ umat,
    const unsigned short* __restrict__ verb_pre,
    const unsigned short* __restrict__ subj_pre,
    const float* __restrict__ objswz,
    float* __restrict__ out)
{
    __shared__ unsigned short Bl[2][8][2][2][64][8];   // 64 KB total

    int bid = blockIdx.x;
    int ct  = bid >> 7;        // 0..1
    int grp = bid & 127;
    int qt  = grp >> 4;        // 0..7
    int pc  = grp & 15;        // 0..15
    int q0 = qt * QT;
    int p0 = pc * PPW;

    int tid  = threadIdx.x;
    int wv   = tid >> 6;       // 0..7
    int lane = tid & 63;
    int g    = lane >> 4;      // 0..3
    int r16  = lane & 15;

    // staging mapping: waves 0-3 stage w, waves 4-7 stage u
    int mat = tid >> 8;                 // 0 = w, 1 = u
    int st  = tid & 255;
    int sq  = st & 31;                  // q within tile (consecutive per wave-half)
    int cg  = st >> 5;                  // 0..7 base i-chunk
    const float* smat = mat ? umat : wmat;
    const float* sbase = smat + (size_t)(cg*8)*(D*D) + (size_t)p0*D + q0 + sq;
    int snt = sq >> 4;
    int sl  = (sq & 15);                // lane-row within block

    // ---- A-fragments: 32 c-rows x K=256, both matrices, register-resident ----
    bf16x8 av[2][8], au[2][8];
#pragma unroll
    for (int mt = 0; mt < 2; ++mt) {
        int mtg = ct*16 + wv*2 + mt;
#pragma unroll
        for (int ks = 0; ks < 8; ++ks) {
            size_t off = (size_t)(((mtg*8 + ks)*64) + lane) * 8;
            av[mt][ks] = *(const bf16x8*)(verb_pre + off);
            au[mt][ks] = *(const bf16x8*)(subj_pre + off);
        }
    }

    f32x4 accF[2][2];
#pragma unroll
    for (int mt = 0; mt < 2; ++mt)
#pragma unroll
        for (int nt = 0; nt < 2; ++nt)
            accF[mt][nt] = (f32x4){0.f, 0.f, 0.f, 0.f};

    float pf[4][8];

    // ---- prologue: load + stage pi=0 into buf 0 ----
#pragma unroll
    for (int m = 0; m < 4; ++m)
#pragma unroll
        for (int j = 0; j < 8; ++j)
            pf[m][j] = sbase[(size_t)(m*64 + j)*(D*D)];

#pragma unroll
    for (int m = 0; m < 4; ++m) {
        bf16x8 vv;
#pragma unroll
        for (int j = 0; j < 8; ++j) vv[j] = (short)f2bf(pf[m][j]);
        int c = cg + 8*m;
        *(bf16x8*)&Bl[0][c >> 2][mat][snt][(c & 3)*16 + sl][0] = vv;
    }

    // obj prefetch for pi=0
    f32x4 ob[2];
#pragma unroll
    for (int mt = 0; mt < 2; ++mt) {
        int mtg = ct*16 + wv*2 + mt;
        ob[mt] = *(const f32x4*)(objswz + ((size_t)mtg*D + p0)*16 + g*4);
    }
    __syncthreads();

#pragma unroll 1
    for (int pi = 0; pi < PPW; ++pi) {
        int cur = pi & 1;
        const unsigned short* bufc = &Bl[cur][0][0][0][0][0];
        unsigned short* bufn = &Bl[cur ^ 1][0][0][0][0][0];

        // ---- issue global loads + obj for pi+1 (latency hides under MFMA) ----
        f32x4 obn[2];
        if (pi + 1 < PPW) {
            const float* nb = sbase + (size_t)(pi + 1)*D;
#pragma unroll
            for (int m = 0; m < 4; ++m)
#pragma unroll
                for (int j = 0; j < 8; ++j)
                    pf[m][j] = nb[(size_t)(m*64 + j)*(D*D)];
#pragma unroll
            for (int mt = 0; mt < 2; ++mt) {
                int mtg = ct*16 + wv*2 + mt;
                obn[mt] = *(const f32x4*)(objswz + ((size_t)mtg*D + p0 + pi + 1)*16 + g*4);
            }
        }

        // ---- MFMA phase on bufc ----
#pragma unroll
        for (int nt = 0; nt < 2; ++nt) {
            f32x4 aA[2], aU[2];
#pragma unroll
            for (int mt = 0; mt < 2; ++mt) {
                aA[mt] = (f32x4){0.f, 0.f, 0.f, 0.f};
                aU[mt] = (f32x4){0.f, 0.f, 0.f, 0.f};
            }
#pragma unroll
            for (int ks = 0; ks < 8; ++ks) {
                // block index: ((ks*2 + mat)*2 + nt)*64 + lane, 8 shorts each
                bf16x8 bw = *(const bf16x8*)(bufc + ((((ks*2 + 0)*2 + nt)*64) + lane)*8);
                bf16x8 bu = *(const bf16x8*)(bufc + ((((ks*2 + 1)*2 + nt)*64) + lane)*8);
#pragma unroll
                for (int mt = 0; mt < 2; ++mt) {
                    aA[mt] = __builtin_amdgcn_mfma_f32_16x16x32_bf16(
                        av[mt][ks], bw, aA[mt], 0, 0, 0);
                    aU[mt] = __builtin_amdgcn_mfma_f32_16x16x32_bf16(
                        au[mt][ks], bu, aU[mt], 0, 0, 0);
                }
            }
#pragma unroll
            for (int mt = 0; mt < 2; ++mt)
#pragma unroll
                for (int rr = 0; rr < 4; ++rr)
                    accF[mt][nt][rr] += ob[mt][rr] * aA[mt][rr] * aU[mt][rr];
        }

        // ---- convert + write pi+1 into bufn (overlaps other waves' MFMA) ----
        if (pi + 1 < PPW) {
#pragma unroll
            for (int m = 0; m < 4; ++m) {
                bf16x8 vv;
#pragma unroll
                for (int j = 0; j < 8; ++j) vv[j] = (short)f2bf(pf[m][j]);
                int c = cg + 8*m;
                *(bf16x8*)(bufn + ((((c >> 2)*2 + mat)*2 + snt)*64 + (c & 3)*16 + sl)*8) = vv;
            }
            ob[0] = obn[0];
            ob[1] = obn[1];
        }
        __syncthreads();
    }

    // ---- accumulate partials over p-chunks ----
#pragma unroll
    for (int mt = 0; mt < 2; ++mt)
#pragma unroll
        for (int nt = 0; nt < 2; ++nt)
#pragma unroll
            for (int rr = 0; rr < 4; ++rr) {
                int c = ct*256 + wv*32 + mt*16 + g*4 + rr;
                int q = q0 + nt*16 + r16;
                atomicAdd(&out[(size_t)c*D + q], accF[mt][nt][rr]);
            }
}

extern "C" void kernel_launch(void* const* d_in, const int* in_sizes, int n_in,
                              void* d_out, int out_size, void* d_ws, size_t ws_size,
                              hipStream_t stream) {
    const int*   subj_id = (const int*)  d_in[0];
    const float* subj_w  = (const float*)d_in[1];
    const int*   verb_id = (const int*)  d_in[2];
    const float* verb_w  = (const float*)d_in[3];
    const int*   obj_id  = (const int*)  d_in[4];
    const float* obj_w   = (const float*)d_in[5];
    const float* emb     = (const float*)d_in[6];
    const float* wmat    = (const float*)d_in[7];
    const float* umat    = (const float*)d_in[8];
    float* out = (float*)d_out;

    unsigned short* verb_pre = (unsigned short*)d_ws;                  // 256 KB
    unsigned short* subj_pre = verb_pre + BATCH*D;                     // 256 KB
    float* objswz = (float*)((char*)d_ws + 2*BATCH*D*sizeof(unsigned short)); // 512 KB

    prep_kernel<<<BATCH, D, 0, stream>>>(subj_id, subj_w, verb_id, verb_w,
                                         obj_id, obj_w, emb,
                                         verb_pre, subj_pre, objswz, out);
    main_kernel<<<256, 512, 0, stream>>>(wmat, umat, verb_pre, subj_pre, objswz, out);
}